// Round 21
// baseline (412.188 us; speedup 1.0000x reference)
//
#include <hip/hip_runtime.h>
#include <hip/hip_fp16.h>

#define C_   256
#define H_   224
#define W_   224
#define HW_  (224 * 224)
#define NWH  28
#define NWW  28
#define NWIN 3136
#define NQUAD 784
#define NTILE 64
#define NFRAG (NTILE * 8 * 64)

#define XN_OFF (1ULL << 20)
#define O_OFF  (XN_OFF + (unsigned long long)NWIN * 32768ULL)
#define WS_NEED (O_OFF + (unsigned long long)NWIN * 32768ULL)   // 206.6MB, R5-proven fits

typedef _Float16 f16x8 __attribute__((ext_vector_type(8)));
typedef float    f32x4 __attribute__((ext_vector_type(4)));

// ---- byte-offset swizzles (bijective XOR; 16B-aligned) ----------------------
__device__ __forceinline__ int xn_off(int row, int col) {
  return (row * 512 + col * 2) ^ ((((row & 7) ^ ((row >> 3) & 7))) << 4);
}
__device__ __forceinline__ int qk_off(int row, int col) {
  return (row * 64 + col * 2) ^ (((row >> 1) & 3) << 4);
}
__device__ __forceinline__ int vt_off(int d, int k) {
  return (d * 128 + k * 2) ^ ((d & 7) << 4);
}
__device__ __forceinline__ int p_off(int row, int col) {
  return (row * 128 + col * 2) ^ ((row & 7) << 4);
}
__device__ __forceinline__ _Float16* xn_at(char* s, int r, int c) { return (_Float16*)(s + xn_off(r, c)); }

// ---- weight fp32 -> fragment-major fp16 ------------------------------------
__global__ void wcvt_kernel(const float* __restrict__ wqkv,
                            const float* __restrict__ wout,
                            _Float16* __restrict__ dst) {
  int f = blockIdx.x * blockDim.x + threadIdx.x;
  if (f >= NFRAG) return;
  int lane = f & 63, kk = (f >> 6) & 7, tile = f >> 9;
  int row = tile * 16 + (lane & 15);
  int col = kk * 32 + (lane >> 4) * 8;
  const float* src = (tile < 48) ? (wqkv + row * 256 + col)
                                 : (wout + (row - 768) * 256 + col);
  f32x4 a = *(const f32x4*)src;
  f32x4 b2 = *(const f32x4*)(src + 4);
  f16x8 r;
#pragma unroll
  for (int q = 0; q < 4; ++q) { r[q] = (_Float16)a[q]; r[q + 4] = (_Float16)b2[q]; }
  *(f16x8*)(dst + (size_t)f * 8) = r;
}

// ============================ kernel A: prep (unchanged) =====================
__global__ __launch_bounds__(512, 1) void prep_kernel(
    const float* __restrict__ x, const float* __restrict__ gamma,
    const float* __restrict__ beta, _Float16* __restrict__ xn_ws) {
  extern __shared__ char smem[];
  float* red = (float*)(smem + 131072);
  float* mrs = (float*)(smem + 147456);
  const int n0 = blockIdx.x;
  const int b  = n0 / 196;
  const int rem = n0 % 196;
  const int wh = rem / 7;
  const int wq = rem % 7;
  const int tid = threadIdx.x;
  const int px4 = (tid & 7) * 4;
  const int row = (tid >> 3) & 7;
  const int chg = tid >> 6;
  const int win = px4 >> 3;
  const int pc  = px4 & 7;
  char* xw = smem + win * 32768;

  {
    const size_t xoff = (size_t)b * C_ * HW_ + (size_t)(wh * 8 + row) * W_ + wq * 32 + px4;
    float s[4] = {0.f, 0.f, 0.f, 0.f}, q[4] = {0.f, 0.f, 0.f, 0.f};
#pragma unroll
    for (int cc = 0; cc < 32; ++cc) {
      const int ch = cc * 8 + chg;
      f32x4 v = *(const f32x4*)(x + xoff + (size_t)ch * HW_);
#pragma unroll
      for (int i = 0; i < 4; ++i) {
        *xn_at(xw, row * 8 + pc + i, ch) = (_Float16)v[i];
        s[i] += v[i]; q[i] += v[i] * v[i];
      }
    }
    const int tq = win * 64 + row * 8 + pc;
#pragma unroll
    for (int i = 0; i < 4; ++i) {
      red[(tq + i) * 8 + chg] = s[i];
      red[2048 + (tq + i) * 8 + chg] = q[i];
    }
  }
  __syncthreads();
  if (tid < 256) {
    float ss = 0.f, s2 = 0.f;
#pragma unroll
    for (int g = 0; g < 8; ++g) { ss += red[tid * 8 + g]; s2 += red[2048 + tid * 8 + g]; }
    float mu  = ss * (1.f / 256.f);
    float var = s2 * (1.f / 256.f) - mu * mu;
    mrs[tid]       = mu;
    mrs[256 + tid] = rsqrtf(var + 1e-5f);
  }
  __syncthreads();
  {
    char* dst = (char*)xn_ws + (size_t)((b * NWH + wh) * NWW + wq * 4) * 32768;
#pragma unroll
    for (int it = 0; it < 16; ++it) {
      const int a   = (it * 512 + tid) * 16;
      const int w2  = a >> 15;
      const int ab  = a & 32767;
      const int tok = ab >> 9;
      const int chb = ((ab & 511) ^ ((((tok & 7) ^ ((tok >> 3) & 7))) << 4)) >> 1;
      f16x8 hv = *(const f16x8*)(smem + a);
      const float mu = mrs[w2 * 64 + tok], rs = mrs[256 + w2 * 64 + tok];
      f32x4 g0 = *(const f32x4*)(gamma + chb), g1 = *(const f32x4*)(gamma + chb + 4);
      f32x4 b0 = *(const f32x4*)(beta + chb),  b1 = *(const f32x4*)(beta + chb + 4);
#pragma unroll
      for (int j = 0; j < 4; ++j) {
        hv[j]     = (_Float16)(((float)hv[j] - mu) * rs * g0[j] + b0[j]);
        hv[j + 4] = (_Float16)(((float)hv[j + 4] - mu) * rs * g1[j] + b1[j]);
      }
      *(f16x8*)(dst + a) = hv;
    }
  }
}

// ============================ kernel B: megattn v8 ===========================
// = v7 (235us) + PAIRED-HEAD staging: one 96KB stage per head pair ->
//   1 convoy + 5 barriers per 2 heads (v7: 2 convoys + 6 barriers).
//   GEMM of head 2j+1 issues BEFORE barrier D, overlapping the partner
//   half-wave's head-2j softmax/PV tail.
// 512 thr = 8 waves; wave w -> window (w>>1), M-half (w&1). LDS 163840 B:
//   [0,98304)       weight pair: section s at s*49152 = q 16K | k 16K | v 16K
//                   p for head parity s lives in dead q region s*49152+winl*8192
//   [98304,147456)  per-window scratch winl*12288: q 4K | k 4K | vT 4K
//   [147456,163840) per-window o buffer 4KB
// Barriers/pair: A (prior pair done: p + scratch reads), B (96KB staged),
// C0 (epilogue h=2j visible), D (after GEMM 2j+1, before its epilogue:
// partner's h=2j scratch reads done), C1.
// VGPR must stay <=128 (R15/R17/R18: the 128-band clamps & spills any extra
// live state; launch-bounds min-waves>1 always spills -- R9/R15).
__global__ __launch_bounds__(512, 1) void megattn_kernel(
    const float* __restrict__ bqkv, const _Float16* __restrict__ w16,
    const _Float16* __restrict__ xn_ws, _Float16* __restrict__ o_ws) {
  extern __shared__ char smem[];
  const int tid = threadIdx.x;
  const int w = tid >> 6, lane = tid & 63, lr = lane & 15, lg = lane >> 4;
  const int winl = w >> 1;
  const int half = w & 1;
  const int r0   = half * 32;
  const int win  = blockIdx.x * 4 + winl;

  // A-fragments for this wave's M-half (32 VGPR), live across all heads
  f16x8 af[2][8];
  {
    const char* xb = (const char*)xn_ws + (size_t)win * 32768;
#pragma unroll
    for (int mi = 0; mi < 2; ++mi)
#pragma unroll
      for (int kk = 0; kk < 8; ++kk)
        af[mi][kk] = *(const f16x8*)(xb + xn_off(r0 + mi * 16 + lr, kk * 32 + lg * 8));
  }

  char* scr   = smem + 98304 + winl * 12288;  // q scratch (stable all head)
  char* kbase = scr + 4096;                   // k scratch
  char* vbase = scr + 8192;                   // vT
  char* obuf  = smem + 147456 + winl * 4096;  // merged o (head-local)
  char* oblob = (char*)o_ws + (size_t)win * 32768;
  const float sc_q = 0.17677669529663687f;    // 1/sqrt(32)

#pragma unroll 1
  for (int j = 0; j < 4; ++j) {               // head pair {2j, 2j+1}
    __syncthreads();   // A: prior pair done with weights (incl p) + scratch
#pragma unroll 1
    for (int s = 0; s < 2; ++s) {             // stage both sections, 1 convoy
      const int hh = 2 * j + s;
      const char* s0 = (const char*)w16 + (size_t)(2 * hh) * 8192;
      const char* s1 = (const char*)w16 + (size_t)(16 + 2 * hh) * 8192;
      const char* s2 = (const char*)w16 + (size_t)(32 + 2 * hh) * 8192;
      char* db = smem + s * 49152;
#pragma unroll
      for (int it = 0; it < 2; ++it) {
        const int o = (it * 512 + tid) * 16;
        *(f32x4*)(db + o)         = *(const f32x4*)(s0 + o);
        *(f32x4*)(db + 16384 + o) = *(const f32x4*)(s1 + o);
        *(f32x4*)(db + 32768 + o) = *(const f32x4*)(s2 + o);
      }
    }
    __syncthreads();   // B: pair staged

#pragma unroll 1
    for (int s = 0; s < 2; ++s) {
      const int h = 2 * j + s;
      char* sect = smem + s * 49152;
      char* pwin = sect + winl * 8192;        // p in dead q region (after GEMM)

      // ---- GEMM: 6 N-tiles x 2 M-tiles from section s = 96 MFMA ----
      f32x4 acc[6][2];
#pragma unroll
      for (int t = 0; t < 6; ++t)
#pragma unroll
        for (int mi = 0; mi < 2; ++mi) acc[t][mi] = (f32x4){0.f, 0.f, 0.f, 0.f};
#pragma unroll
      for (int kk = 0; kk < 8; ++kk) {
        const int fo = (kk * 64 + lane) * 16;
        f16x8 b0 = *(const f16x8*)(sect + fo);
        f16x8 b1 = *(const f16x8*)(sect + 8192 + fo);
        f16x8 b2 = *(const f16x8*)(sect + 16384 + fo);
        f16x8 b3 = *(const f16x8*)(sect + 24576 + fo);
        f16x8 b4 = *(const f16x8*)(sect + 32768 + fo);
        f16x8 b5 = *(const f16x8*)(sect + 40960 + fo);
#pragma unroll
        for (int mi = 0; mi < 2; ++mi) {
          acc[0][mi] = __builtin_amdgcn_mfma_f32_16x16x32_f16(af[mi][kk], b0, acc[0][mi], 0, 0, 0);
          acc[1][mi] = __builtin_amdgcn_mfma_f32_16x16x32_f16(af[mi][kk], b1, acc[1][mi], 0, 0, 0);
          acc[2][mi] = __builtin_amdgcn_mfma_f32_16x16x32_f16(af[mi][kk], b2, acc[2][mi], 0, 0, 0);
          acc[3][mi] = __builtin_amdgcn_mfma_f32_16x16x32_f16(af[mi][kk], b3, acc[3][mi], 0, 0, 0);
          acc[4][mi] = __builtin_amdgcn_mfma_f32_16x16x32_f16(af[mi][kk], b4, acc[4][mi], 0, 0, 0);
          acc[5][mi] = __builtin_amdgcn_mfma_f32_16x16x32_f16(af[mi][kk], b5, acc[5][mi], 0, 0, 0);
        }
      }
      if (s == 1) __syncthreads();  // D: partner's h=2j scratch reads complete

      // ---- epilogue: q scaled+bias, k bias, vT (this wave's token half) ----
#pragma unroll
      for (int t2 = 0; t2 < 2; ++t2) {
        const float bq = bqkv[h * 32 + t2 * 16 + lr];
        const float bk = bqkv[256 + h * 32 + t2 * 16 + lr];
        const float bv = bqkv[512 + h * 32 + t2 * 16 + lr];
#pragma unroll
        for (int mi = 0; mi < 2; ++mi)
#pragma unroll
          for (int i = 0; i < 4; ++i) {
            const int trow = r0 + mi * 16 + lg * 4 + i;
            *(_Float16*)(scr + qk_off(trow, t2 * 16 + lr))   = (_Float16)((acc[t2][mi][i] + bq) * sc_q);
            *(_Float16*)(kbase + qk_off(trow, t2 * 16 + lr)) = (_Float16)(acc[2 + t2][mi][i] + bk);
            *(_Float16*)(vbase + vt_off(t2 * 16 + lr, trow)) = (_Float16)(acc[4 + t2][mi][i] + bv);
          }
      }
      __syncthreads();   // C_s: both halves' q/k/vT visible

      // ---- scores: own q rows x ALL k rows ----
      f16x8 qa[2], kb[4];
#pragma unroll
      for (int mi = 0; mi < 2; ++mi)
        qa[mi] = *(const f16x8*)(scr + qk_off(r0 + mi * 16 + lr, lg * 8));
#pragma unroll
      for (int ni = 0; ni < 4; ++ni)
        kb[ni] = *(const f16x8*)(kbase + qk_off(ni * 16 + lr, lg * 8));

      float oinv[2][4];
#pragma unroll
      for (int mi = 0; mi < 2; ++mi) {
        f32x4 s4[4];
#pragma unroll
        for (int ni = 0; ni < 4; ++ni) {
          f32x4 z = {0.f, 0.f, 0.f, 0.f};
          s4[ni] = __builtin_amdgcn_mfma_f32_16x16x32_f16(qa[mi], kb[ni], z, 0, 0, 0);
        }
#pragma unroll
        for (int i = 0; i < 4; ++i) {
          float m = fmaxf(fmaxf(s4[0][i], s4[1][i]), fmaxf(s4[2][i], s4[3][i]));
          m = fmaxf(m, __shfl_xor(m, 1));
          m = fmaxf(m, __shfl_xor(m, 2));
          m = fmaxf(m, __shfl_xor(m, 4));
          m = fmaxf(m, __shfl_xor(m, 8));
          float ssum = 0.f;
#pragma unroll
          for (int ni = 0; ni < 4; ++ni) {
            float e = __expf(s4[ni][i] - m);
            s4[ni][i] = e;
            ssum += e;
          }
          ssum += __shfl_xor(ssum, 1);
          ssum += __shfl_xor(ssum, 2);
          ssum += __shfl_xor(ssum, 4);
          ssum += __shfl_xor(ssum, 8);
          oinv[mi][i] = 1.f / ssum;
        }
        // p -> wave-private rows in dead q region of section s (no barrier)
#pragma unroll
        for (int ni = 0; ni < 4; ++ni)
#pragma unroll
          for (int i = 0; i < 4; ++i)
            *(_Float16*)(pwin + p_off(r0 + mi * 16 + lg * 4 + i, ni * 16 + lr)) = (_Float16)s4[ni][i];
      }
      // ---- PV: own p rows x all vT ----
      f32x4 oacc[2][2];
#pragma unroll
      for (int mi = 0; mi < 2; ++mi)
#pragma unroll
        for (int nt2 = 0; nt2 < 2; ++nt2) oacc[mi][nt2] = (f32x4){0.f, 0.f, 0.f, 0.f};
#pragma unroll
      for (int ks2 = 0; ks2 < 2; ++ks2) {
        f16x8 pa[2];
#pragma unroll
        for (int mi = 0; mi < 2; ++mi)
          pa[mi] = *(const f16x8*)(pwin + p_off(r0 + mi * 16 + lr, ks2 * 32 + lg * 8));
#pragma unroll
        for (int nt2 = 0; nt2 < 2; ++nt2) {
          f16x8 vb = *(const f16x8*)(vbase + vt_off(nt2 * 16 + lr, ks2 * 32 + lg * 8));
#pragma unroll
          for (int mi = 0; mi < 2; ++mi)
            oacc[mi][nt2] = __builtin_amdgcn_mfma_f32_16x16x32_f16(pa[mi], vb, oacc[mi][nt2], 0, 0, 0);
        }
      }
      // ---- o-head: assemble own rows in obuf, dump own 2KB half ----
#pragma unroll
      for (int mi = 0; mi < 2; ++mi)
#pragma unroll
        for (int nt2 = 0; nt2 < 2; ++nt2)
#pragma unroll
          for (int i = 0; i < 4; ++i)
            *(_Float16*)(obuf + qk_off(r0 + mi * 16 + lg * 4 + i, nt2 * 16 + lr)) =
                (_Float16)(oacc[mi][nt2][i] * oinv[mi][i]);
#pragma unroll
      for (int jj = 0; jj < 2; ++jj)
        *(f32x4*)(oblob + h * 4096 + half * 2048 + lane * 32 + jj * 16) =
            *(const f32x4*)(obuf + half * 2048 + lane * 32 + jj * 16);
    }
  }
}

// ============================ kernel C: out-proj (unchanged) =================
__device__ __forceinline__ f16x8 frag16(const _Float16* __restrict__ w16,
                                        int gt, int kk, int lane) {
  return *(const f16x8*)(w16 + ((size_t)((gt * 8 + kk) * 64 + lane)) * 8);
}
__global__ __launch_bounds__(512, 1) void outproj_kernel(
    const _Float16* __restrict__ o_ws, const _Float16* __restrict__ w16,
    const float* __restrict__ bout, float* __restrict__ out) {
  extern __shared__ char smem[];
  const int n0 = blockIdx.x;
  const int b  = n0 / 196;
  const int rem = n0 % 196;
  const int wh = rem / 7;
  const int wq = rem % 7;
  const int tid = threadIdx.x;
  const int w = tid >> 6, lane = tid & 63, lr = lane & 15, lg = lane >> 4;

  {
    const char* src = (const char*)o_ws + (size_t)((b * NWH + wh) * NWW + wq * 4) * 32768;
#pragma unroll
    for (int it = 0; it < 16; ++it) {
      const int off = (it * 512 + tid) * 16;
      *(f32x4*)(smem + off) = *(const f32x4*)(src + off);
    }
  }
  __syncthreads();

  f32x4 acc[4][2][4];
#pragma unroll
  for (int wi = 0; wi < 4; ++wi)
#pragma unroll
    for (int t = 0; t < 2; ++t)
#pragma unroll
      for (int mi = 0; mi < 4; ++mi) acc[wi][t][mi] = (f32x4){0.f, 0.f, 0.f, 0.f};

#pragma unroll
  for (int kk = 0; kk < 8; ++kk) {   // kk == head of the o blob
    f16x8 bf0 = frag16(w16, 48 + w * 2 + 0, kk, lane);
    f16x8 bf1 = frag16(w16, 48 + w * 2 + 1, kk, lane);
#pragma unroll
    for (int wi = 0; wi < 4; ++wi) {
      f16x8 af[4];
#pragma unroll
      for (int mi = 0; mi < 4; ++mi)
        af[mi] = *(const f16x8*)(smem + wi * 32768 + kk * 4096 + qk_off(mi * 16 + lr, lg * 8));
#pragma unroll
      for (int mi = 0; mi < 4; ++mi) {
        acc[wi][0][mi] = __builtin_amdgcn_mfma_f32_16x16x32_f16(af[mi], bf0, acc[wi][0][mi], 0, 0, 0);
        acc[wi][1][mi] = __builtin_amdgcn_mfma_f32_16x16x32_f16(af[mi], bf1, acc[wi][1][mi], 0, 0, 0);
      }
    }
  }

#pragma unroll
  for (int ntl = 0; ntl < 2; ++ntl) {
    const int och = w * 32 + ntl * 16 + lr;
    const float bias = bout[och];
    float* ob = out + ((size_t)(b * C_ + och) * H_ + wh * 8) * W_ + wq * 32;
#pragma unroll
    for (int mi = 0; mi < 4; ++mi) {
      const int tb = mi * 16 + lg * 4;
      const int ro = (tb >> 3) * W_ + (tb & 7);
#pragma unroll
      for (int wi = 0; wi < 4; ++wi) {
        f32x4 ov;
#pragma unroll
        for (int i = 0; i < 4; ++i) ov[i] = acc[wi][ntl][mi][i] + bias;
        *(f32x4*)&ob[ro + wi * 8] = ov;
      }
    }
  }
}

extern "C" void kernel_launch(void* const* d_in, const int* in_sizes, int n_in,
                              void* d_out, int out_size, void* d_ws, size_t ws_size,
                              hipStream_t stream) {
  (void)in_sizes; (void)n_in; (void)out_size; (void)ws_size;
  const float* x     = (const float*)d_in[0];
  const float* gamma = (const float*)d_in[1];
  const float* beta  = (const float*)d_in[2];
  const float* wqkv  = (const float*)d_in[3];
  const float* bqkv  = (const float*)d_in[4];
  const float* wout  = (const float*)d_in[5];
  const float* bout  = (const float*)d_in[6];
  float* out = (float*)d_out;

  _Float16* w16   = (_Float16*)d_ws;
  _Float16* xn_ws = (_Float16*)((char*)d_ws + XN_OFF);
  _Float16* o_ws  = (_Float16*)((char*)d_ws + O_OFF);

  static int attr_set = 0;
  if (!attr_set) {
    (void)hipFuncSetAttribute((const void*)prep_kernel,
                              hipFuncAttributeMaxDynamicSharedMemorySize, 149504);
    (void)hipFuncSetAttribute((const void*)megattn_kernel,
                              hipFuncAttributeMaxDynamicSharedMemorySize, 163840);
    (void)hipFuncSetAttribute((const void*)outproj_kernel,
                              hipFuncAttributeMaxDynamicSharedMemorySize, 131072);
    attr_set = 1;
  }

  wcvt_kernel<<<NFRAG / 256, 256, 0, stream>>>(wqkv, wout, w16);
  prep_kernel<<<NQUAD, 512, 149504, stream>>>(x, gamma, beta, xn_ws);
  megattn_kernel<<<NQUAD, 512, 163840, stream>>>(bqkv, w16, xn_ws, o_ws);
  outproj_kernel<<<NQUAD, 512, 131072, stream>>>(o_ws, w16, bout, out);
}

// Round 22
// 410.038 us; speedup vs baseline: 1.0052x; 1.0052x over previous
//
#include <hip/hip_runtime.h>
#include <hip/hip_fp16.h>

#define C_   256
#define H_   224
#define W_   224
#define HW_  (224 * 224)
#define NWH  28
#define NWW  28
#define NWIN 3136
#define NQUAD 784
#define NTILE 64
#define NFRAG (NTILE * 8 * 64)

#define XN_OFF (1ULL << 20)
#define O_OFF  (XN_OFF + (unsigned long long)NWIN * 32768ULL)
#define WS_NEED (O_OFF + (unsigned long long)NWIN * 32768ULL)   // 206.6MB, R5-proven fits

typedef _Float16 f16x8 __attribute__((ext_vector_type(8)));
typedef float    f32x4 __attribute__((ext_vector_type(4)));

// ---- byte-offset swizzles (bijective XOR; 16B-aligned) ----------------------
__device__ __forceinline__ int xn_off(int row, int col) {
  return (row * 512 + col * 2) ^ ((((row & 7) ^ ((row >> 3) & 7))) << 4);
}
__device__ __forceinline__ int qk_off(int row, int col) {
  return (row * 64 + col * 2) ^ (((row >> 1) & 3) << 4);
}
__device__ __forceinline__ int vt_off(int d, int k) {
  return (d * 128 + k * 2) ^ ((d & 7) << 4);
}
__device__ __forceinline__ int p_off(int row, int col) {
  return (row * 128 + col * 2) ^ ((row & 7) << 4);
}
__device__ __forceinline__ _Float16* xn_at(char* s, int r, int c) { return (_Float16*)(s + xn_off(r, c)); }

// ---- weight fp32 -> fragment-major fp16 ------------------------------------
__global__ void wcvt_kernel(const float* __restrict__ wqkv,
                            const float* __restrict__ wout,
                            _Float16* __restrict__ dst) {
  int f = blockIdx.x * blockDim.x + threadIdx.x;
  if (f >= NFRAG) return;
  int lane = f & 63, kk = (f >> 6) & 7, tile = f >> 9;
  int row = tile * 16 + (lane & 15);
  int col = kk * 32 + (lane >> 4) * 8;
  const float* src = (tile < 48) ? (wqkv + row * 256 + col)
                                 : (wout + (row - 768) * 256 + col);
  f32x4 a = *(const f32x4*)src;
  f32x4 b2 = *(const f32x4*)(src + 4);
  f16x8 r;
#pragma unroll
  for (int q = 0; q < 4; ++q) { r[q] = (_Float16)a[q]; r[q + 4] = (_Float16)b2[q]; }
  *(f16x8*)(dst + (size_t)f * 8) = r;
}

// ============================ kernel A: prep =================================
__global__ __launch_bounds__(512, 1) void prep_kernel(
    const float* __restrict__ x, const float* __restrict__ gamma,
    const float* __restrict__ beta, _Float16* __restrict__ xn_ws) {
  extern __shared__ char smem[];
  float* red = (float*)(smem + 131072);
  float* mrs = (float*)(smem + 147456);
  const int n0 = blockIdx.x;
  const int b  = n0 / 196;
  const int rem = n0 % 196;
  const int wh = rem / 7;
  const int wq = rem % 7;
  const int tid = threadIdx.x;
  const int px4 = (tid & 7) * 4;
  const int row = (tid >> 3) & 7;
  const int chg = tid >> 6;
  const int win = px4 >> 3;
  const int pc  = px4 & 7;
  char* xw = smem + win * 32768;

  {
    const size_t xoff = (size_t)b * C_ * HW_ + (size_t)(wh * 8 + row) * W_ + wq * 32 + px4;
    float s[4] = {0.f, 0.f, 0.f, 0.f}, q[4] = {0.f, 0.f, 0.f, 0.f};
#pragma unroll
    for (int cc = 0; cc < 32; ++cc) {
      const int ch = cc * 8 + chg;
      f32x4 v = *(const f32x4*)(x + xoff + (size_t)ch * HW_);
#pragma unroll
      for (int i = 0; i < 4; ++i) {
        *xn_at(xw, row * 8 + pc + i, ch) = (_Float16)v[i];
        s[i] += v[i]; q[i] += v[i] * v[i];
      }
    }
    const int tq = win * 64 + row * 8 + pc;
#pragma unroll
    for (int i = 0; i < 4; ++i) {
      red[(tq + i) * 8 + chg] = s[i];
      red[2048 + (tq + i) * 8 + chg] = q[i];
    }
  }
  __syncthreads();
  if (tid < 256) {
    float ss = 0.f, s2 = 0.f;
#pragma unroll
    for (int g = 0; g < 8; ++g) { ss += red[tid * 8 + g]; s2 += red[2048 + tid * 8 + g]; }
    float mu  = ss * (1.f / 256.f);
    float var = s2 * (1.f / 256.f) - mu * mu;
    mrs[tid]       = mu;
    mrs[256 + tid] = rsqrtf(var + 1e-5f);
  }
  __syncthreads();
  {
    char* dst = (char*)xn_ws + (size_t)((b * NWH + wh) * NWW + wq * 4) * 32768;
#pragma unroll
    for (int it = 0; it < 16; ++it) {
      const int a   = (it * 512 + tid) * 16;
      const int w2  = a >> 15;
      const int ab  = a & 32767;
      const int tok = ab >> 9;
      const int chb = ((ab & 511) ^ ((((tok & 7) ^ ((tok >> 3) & 7))) << 4)) >> 1;
      f16x8 hv = *(const f16x8*)(smem + a);
      const float mu = mrs[w2 * 64 + tok], rs = mrs[256 + w2 * 64 + tok];
      f32x4 g0 = *(const f32x4*)(gamma + chb), g1 = *(const f32x4*)(gamma + chb + 4);
      f32x4 b0 = *(const f32x4*)(beta + chb),  b1 = *(const f32x4*)(beta + chb + 4);
#pragma unroll
      for (int j = 0; j < 4; ++j) {
        hv[j]     = (_Float16)(((float)hv[j] - mu) * rs * g0[j] + b0[j]);
        hv[j + 4] = (_Float16)(((float)hv[j + 4] - mu) * rs * g1[j] + b1[j]);
      }
      *(f16x8*)(dst + a) = hv;
    }
  }
}

// ============================ kernel B: megattn v7 (FINAL, 235us) ============
// R14-v3 + p relocated into the DEAD q-weight region (wave-private) ->
// barrier C2 deleted. 512 thr = 8 waves; wave w -> window (w>>1), M-half (w&1).
// LDS 114688 B:
//   [0,49152)       head weights q|k|v (16KB each); [0,16384) doubles as
//                   p [2 win][64][64] fp16 after each head's GEMM
//   [49152,98304)   per-window scratch winl*12288: q 4K | k 4K | vT 4K
//   [98304,114688)  per-window o buffer 4KB
// 3 barriers/head: A (restage safe), B (weights staged), C (epilogue visible).
// VGPR = 124 (proven). Session-established rules: never launch-bounds
// min-waves>1 (R9/R15 spills); never add live state crossing the GEMM
// (R17/R18 clamp+spill at the 128-VGPR band); v8's paired staging = neutral.
__global__ __launch_bounds__(512, 1) void megattn_kernel(
    const float* __restrict__ bqkv, const _Float16* __restrict__ w16,
    const _Float16* __restrict__ xn_ws, _Float16* __restrict__ o_ws) {
  extern __shared__ char smem[];
  const int tid = threadIdx.x;
  const int w = tid >> 6, lane = tid & 63, lr = lane & 15, lg = lane >> 4;
  const int winl = w >> 1;
  const int half = w & 1;
  const int r0   = half * 32;
  const int win  = blockIdx.x * 4 + winl;

  // A-fragments for this wave's M-half (64 VGPR)
  f16x8 af[2][8];
  {
    const char* xb = (const char*)xn_ws + (size_t)win * 32768;
#pragma unroll
    for (int mi = 0; mi < 2; ++mi)
#pragma unroll
      for (int kk = 0; kk < 8; ++kk)
        af[mi][kk] = *(const f16x8*)(xb + xn_off(r0 + mi * 16 + lr, kk * 32 + lg * 8));
  }

  char* scr   = smem + 49152 + winl * 12288;  // q scratch (stable all head)
  char* kbase = scr + 4096;                   // k scratch
  char* vbase = scr + 8192;                   // vT
  char* pwin  = smem + winl * 8192;           // p in dead q-weight area
  char* obuf  = smem + 98304 + winl * 4096;   // merged o (head-local)
  char* oblob = (char*)o_ws + (size_t)win * 32768;
  const float sc_q = 0.17677669529663687f;    // 1/sqrt(32)

#pragma unroll 1
  for (int h = 0; h < 8; ++h) {
    __syncthreads();   // A: prior head done with weights (incl. p region)
    {
      const char* s0 = (const char*)w16 + (size_t)(2 * h) * 8192;
      const char* s1 = (const char*)w16 + (size_t)(16 + 2 * h) * 8192;
      const char* s2 = (const char*)w16 + (size_t)(32 + 2 * h) * 8192;
#pragma unroll
      for (int it = 0; it < 2; ++it) {
        const int o = (it * 512 + tid) * 16;
        *(f32x4*)(smem + o)         = *(const f32x4*)(s0 + o);
        *(f32x4*)(smem + 16384 + o) = *(const f32x4*)(s1 + o);
        *(f32x4*)(smem + 32768 + o) = *(const f32x4*)(s2 + o);
      }
    }
    __syncthreads();   // B: weights staged

    // ---- GEMM: 6 N-tiles x 2 M-tiles (this wave's half) = 96 MFMA ----
    f32x4 acc[6][2];
#pragma unroll
    for (int t = 0; t < 6; ++t)
#pragma unroll
      for (int mi = 0; mi < 2; ++mi) acc[t][mi] = (f32x4){0.f, 0.f, 0.f, 0.f};
#pragma unroll
    for (int kk = 0; kk < 8; ++kk) {
      const int fo = (kk * 64 + lane) * 16;
      f16x8 b0 = *(const f16x8*)(smem + fo);
      f16x8 b1 = *(const f16x8*)(smem + 8192 + fo);
      f16x8 b2 = *(const f16x8*)(smem + 16384 + fo);
      f16x8 b3 = *(const f16x8*)(smem + 24576 + fo);
      f16x8 b4 = *(const f16x8*)(smem + 32768 + fo);
      f16x8 b5 = *(const f16x8*)(smem + 40960 + fo);
#pragma unroll
      for (int mi = 0; mi < 2; ++mi) {
        acc[0][mi] = __builtin_amdgcn_mfma_f32_16x16x32_f16(af[mi][kk], b0, acc[0][mi], 0, 0, 0);
        acc[1][mi] = __builtin_amdgcn_mfma_f32_16x16x32_f16(af[mi][kk], b1, acc[1][mi], 0, 0, 0);
        acc[2][mi] = __builtin_amdgcn_mfma_f32_16x16x32_f16(af[mi][kk], b2, acc[2][mi], 0, 0, 0);
        acc[3][mi] = __builtin_amdgcn_mfma_f32_16x16x32_f16(af[mi][kk], b3, acc[3][mi], 0, 0, 0);
        acc[4][mi] = __builtin_amdgcn_mfma_f32_16x16x32_f16(af[mi][kk], b4, acc[4][mi], 0, 0, 0);
        acc[5][mi] = __builtin_amdgcn_mfma_f32_16x16x32_f16(af[mi][kk], b5, acc[5][mi], 0, 0, 0);
      }
    }
    // ---- epilogue: q scaled+bias, k bias, vT (this wave's token half) ----
#pragma unroll
    for (int t2 = 0; t2 < 2; ++t2) {
      const float bq = bqkv[h * 32 + t2 * 16 + lr];
      const float bk = bqkv[256 + h * 32 + t2 * 16 + lr];
      const float bv = bqkv[512 + h * 32 + t2 * 16 + lr];
#pragma unroll
      for (int mi = 0; mi < 2; ++mi)
#pragma unroll
        for (int i = 0; i < 4; ++i) {
          const int trow = r0 + mi * 16 + lg * 4 + i;
          *(_Float16*)(scr + qk_off(trow, t2 * 16 + lr))   = (_Float16)((acc[t2][mi][i] + bq) * sc_q);
          *(_Float16*)(kbase + qk_off(trow, t2 * 16 + lr)) = (_Float16)(acc[2 + t2][mi][i] + bk);
          *(_Float16*)(vbase + vt_off(t2 * 16 + lr, trow)) = (_Float16)(acc[4 + t2][mi][i] + bv);
        }
    }
    __syncthreads();   // C: both halves' q/k/vT visible (GEMM also fully done)

    // ---- scores: own q rows x ALL k rows ----
    f16x8 qa[2], kb[4];
#pragma unroll
    for (int mi = 0; mi < 2; ++mi)
      qa[mi] = *(const f16x8*)(scr + qk_off(r0 + mi * 16 + lr, lg * 8));
#pragma unroll
    for (int ni = 0; ni < 4; ++ni)
      kb[ni] = *(const f16x8*)(kbase + qk_off(ni * 16 + lr, lg * 8));

    float oinv[2][4];
#pragma unroll
    for (int mi = 0; mi < 2; ++mi) {
      f32x4 s4[4];
#pragma unroll
      for (int ni = 0; ni < 4; ++ni) {
        f32x4 z = {0.f, 0.f, 0.f, 0.f};
        s4[ni] = __builtin_amdgcn_mfma_f32_16x16x32_f16(qa[mi], kb[ni], z, 0, 0, 0);
      }
#pragma unroll
      for (int i = 0; i < 4; ++i) {
        float m = fmaxf(fmaxf(s4[0][i], s4[1][i]), fmaxf(s4[2][i], s4[3][i]));
        m = fmaxf(m, __shfl_xor(m, 1));
        m = fmaxf(m, __shfl_xor(m, 2));
        m = fmaxf(m, __shfl_xor(m, 4));
        m = fmaxf(m, __shfl_xor(m, 8));
        float s = 0.f;
#pragma unroll
        for (int ni = 0; ni < 4; ++ni) {
          float e = __expf(s4[ni][i] - m);
          s4[ni][i] = e;
          s += e;
        }
        s += __shfl_xor(s, 1);
        s += __shfl_xor(s, 2);
        s += __shfl_xor(s, 4);
        s += __shfl_xor(s, 8);
        oinv[mi][i] = 1.f / s;
      }
      // p -> wave-private rows in dead q-weight region (no barrier needed)
#pragma unroll
      for (int ni = 0; ni < 4; ++ni)
#pragma unroll
        for (int i = 0; i < 4; ++i)
          *(_Float16*)(pwin + p_off(r0 + mi * 16 + lg * 4 + i, ni * 16 + lr)) = (_Float16)s4[ni][i];
    }
    // ---- PV: own p rows x all vT ----
    f32x4 oacc[2][2];
#pragma unroll
    for (int mi = 0; mi < 2; ++mi)
#pragma unroll
      for (int nt2 = 0; nt2 < 2; ++nt2) oacc[mi][nt2] = (f32x4){0.f, 0.f, 0.f, 0.f};
#pragma unroll
    for (int ks2 = 0; ks2 < 2; ++ks2) {
      f16x8 pa[2];
#pragma unroll
      for (int mi = 0; mi < 2; ++mi)
        pa[mi] = *(const f16x8*)(pwin + p_off(r0 + mi * 16 + lr, ks2 * 32 + lg * 8));
#pragma unroll
      for (int nt2 = 0; nt2 < 2; ++nt2) {
        f16x8 vb = *(const f16x8*)(vbase + vt_off(nt2 * 16 + lr, ks2 * 32 + lg * 8));
#pragma unroll
        for (int mi = 0; mi < 2; ++mi)
          oacc[mi][nt2] = __builtin_amdgcn_mfma_f32_16x16x32_f16(pa[mi], vb, oacc[mi][nt2], 0, 0, 0);
      }
    }
    // ---- o-head: assemble own rows in obuf, dump own 2KB half ----
#pragma unroll
    for (int mi = 0; mi < 2; ++mi)
#pragma unroll
      for (int nt2 = 0; nt2 < 2; ++nt2)
#pragma unroll
        for (int i = 0; i < 4; ++i)
          *(_Float16*)(obuf + qk_off(r0 + mi * 16 + lg * 4 + i, nt2 * 16 + lr)) =
              (_Float16)(oacc[mi][nt2][i] * oinv[mi][i]);
#pragma unroll
    for (int j = 0; j < 2; ++j)
      *(f32x4*)(oblob + h * 4096 + half * 2048 + lane * 32 + j * 16) =
          *(const f32x4*)(obuf + half * 2048 + lane * 32 + j * 16);
  }
}

// ============================ kernel C: out-proj =============================
__device__ __forceinline__ f16x8 frag16(const _Float16* __restrict__ w16,
                                        int gt, int kk, int lane) {
  return *(const f16x8*)(w16 + ((size_t)((gt * 8 + kk) * 64 + lane)) * 8);
}
__global__ __launch_bounds__(512, 1) void outproj_kernel(
    const _Float16* __restrict__ o_ws, const _Float16* __restrict__ w16,
    const float* __restrict__ bout, float* __restrict__ out) {
  extern __shared__ char smem[];
  const int n0 = blockIdx.x;
  const int b  = n0 / 196;
  const int rem = n0 % 196;
  const int wh = rem / 7;
  const int wq = rem % 7;
  const int tid = threadIdx.x;
  const int w = tid >> 6, lane = tid & 63, lr = lane & 15, lg = lane >> 4;

  {
    const char* src = (const char*)o_ws + (size_t)((b * NWH + wh) * NWW + wq * 4) * 32768;
#pragma unroll
    for (int it = 0; it < 16; ++it) {
      const int off = (it * 512 + tid) * 16;
      *(f32x4*)(smem + off) = *(const f32x4*)(src + off);
    }
  }
  __syncthreads();

  f32x4 acc[4][2][4];
#pragma unroll
  for (int wi = 0; wi < 4; ++wi)
#pragma unroll
    for (int t = 0; t < 2; ++t)
#pragma unroll
      for (int mi = 0; mi < 4; ++mi) acc[wi][t][mi] = (f32x4){0.f, 0.f, 0.f, 0.f};

#pragma unroll
  for (int kk = 0; kk < 8; ++kk) {   // kk == head of the o blob
    f16x8 bf0 = frag16(w16, 48 + w * 2 + 0, kk, lane);
    f16x8 bf1 = frag16(w16, 48 + w * 2 + 1, kk, lane);
#pragma unroll
    for (int wi = 0; wi < 4; ++wi) {
      f16x8 af[4];
#pragma unroll
      for (int mi = 0; mi < 4; ++mi)
        af[mi] = *(const f16x8*)(smem + wi * 32768 + kk * 4096 + qk_off(mi * 16 + lr, lg * 8));
#pragma unroll
      for (int mi = 0; mi < 4; ++mi) {
        acc[wi][0][mi] = __builtin_amdgcn_mfma_f32_16x16x32_f16(af[mi], bf0, acc[wi][0][mi], 0, 0, 0);
        acc[wi][1][mi] = __builtin_amdgcn_mfma_f32_16x16x32_f16(af[mi], bf1, acc[wi][1][mi], 0, 0, 0);
      }
    }
  }

#pragma unroll
  for (int ntl = 0; ntl < 2; ++ntl) {
    const int och = w * 32 + ntl * 16 + lr;
    const float bias = bout[och];
    float* ob = out + ((size_t)(b * C_ + och) * H_ + wh * 8) * W_ + wq * 32;
#pragma unroll
    for (int mi = 0; mi < 4; ++mi) {
      const int tb = mi * 16 + lg * 4;
      const int ro = (tb >> 3) * W_ + (tb & 7);
#pragma unroll
      for (int wi = 0; wi < 4; ++wi) {
        f32x4 ov;
#pragma unroll
        for (int i = 0; i < 4; ++i) ov[i] = acc[wi][ntl][mi][i] + bias;
        *(f32x4*)&ob[ro + wi * 8] = ov;
      }
    }
  }
}

extern "C" void kernel_launch(void* const* d_in, const int* in_sizes, int n_in,
                              void* d_out, int out_size, void* d_ws, size_t ws_size,
                              hipStream_t stream) {
  (void)in_sizes; (void)n_in; (void)out_size; (void)ws_size;
  const float* x     = (const float*)d_in[0];
  const float* gamma = (const float*)d_in[1];
  const float* beta  = (const float*)d_in[2];
  const float* wqkv  = (const float*)d_in[3];
  const float* bqkv  = (const float*)d_in[4];
  const float* wout  = (const float*)d_in[5];
  const float* bout  = (const float*)d_in[6];
  float* out = (float*)d_out;

  _Float16* w16   = (_Float16*)d_ws;
  _Float16* xn_ws = (_Float16*)((char*)d_ws + XN_OFF);
  _Float16* o_ws  = (_Float16*)((char*)d_ws + O_OFF);

  static int attr_set = 0;
  if (!attr_set) {
    (void)hipFuncSetAttribute((const void*)prep_kernel,
                              hipFuncAttributeMaxDynamicSharedMemorySize, 149504);
    (void)hipFuncSetAttribute((const void*)megattn_kernel,
                              hipFuncAttributeMaxDynamicSharedMemorySize, 114688);
    (void)hipFuncSetAttribute((const void*)outproj_kernel,
                              hipFuncAttributeMaxDynamicSharedMemorySize, 131072);
    attr_set = 1;
  }

  wcvt_kernel<<<NFRAG / 256, 256, 0, stream>>>(wqkv, wout, w16);
  prep_kernel<<<NQUAD, 512, 149504, stream>>>(x, gamma, beta, xn_ws);
  megattn_kernel<<<NQUAD, 512, 114688, stream>>>(bqkv, w16, xn_ws, o_ws);
  outproj_kernel<<<NQUAD, 512, 131072, stream>>>(o_ws, w16, bout, out);
}